// Round 2
// baseline (729.224 us; speedup 1.0000x reference)
//
#include <hip/hip_runtime.h>
#include <stdint.h>

typedef __bf16 bf16x8 __attribute__((ext_vector_type(8)));
typedef float f32x16 __attribute__((ext_vector_type(16)));

#define NN 4096
#define FF 64

// round-to-nearest-even fp32 -> bf16
__device__ __forceinline__ unsigned short f2bf(float x) {
    unsigned int u = __builtin_bit_cast(unsigned int, x);
    unsigned int r = u + 0x7fffu + ((u >> 16) & 1u);
    return (unsigned short)(r >> 16);
}

__device__ __forceinline__ unsigned int pk2(float lo, float hi) {
    return (unsigned int)f2bf(lo) | ((unsigned int)f2bf(hi) << 16);
}

// Pass 1: ann[b][m][f] fp32 -> annT[b][f][m] bf16 (LDS-tiled transpose)
__global__ __launch_bounds__(256) void annT_kernel(const float* __restrict__ ann,
                                                   unsigned short* __restrict__ annT) {
    __shared__ unsigned short tile[FF * 66];
    int b = blockIdx.x >> 6;
    int m0 = (blockIdx.x & 63) << 6;
    int t = threadIdx.x;
    int f = t & 63;
    int ml = t >> 6;
    const float* src = ann + ((size_t)(b * NN + m0)) * FF;
#pragma unroll
    for (int it = 0; it < 16; ++it) {
        int m = it * 4 + ml;
        tile[f * 66 + m] = f2bf(src[(size_t)m * FF + f]);
    }
    __syncthreads();
    int m2 = (t & 31) * 2;
    int fr = t >> 5;
    unsigned short* dst = annT + (size_t)b * FF * NN + m0;
#pragma unroll
    for (int it = 0; it < 8; ++it) {
        int fo = it * 8 + fr;
        unsigned int lo = tile[fo * 66 + m2];
        unsigned int hi = tile[fo * 66 + m2 + 1];
        *(unsigned int*)(dst + (size_t)fo * NN + m2) = lo | (hi << 16);
    }
}

// Pass 2: zero-LDS, zero-barrier streaming MFMA.
// One wave per 32-row x 64-f output tile. A fragments loaded straight from
// global fp32 (cvt in regs); B fragments from L2-resident annT bf16.
__global__ __launch_bounds__(64) void gconv_kernel(const float* __restrict__ A,
                                                   const unsigned short* __restrict__ annT,
                                                   const float* __restrict__ bias,
                                                   float* __restrict__ out) {
    int bi = blockIdx.x;
    int b = bi & 7;               // batch == XCD -> annT[b] stays in that XCD's L2
    int n0 = (bi >> 3) << 5;      // 128 row-tiles per batch
    int lane = threadIdx.x;       // 0..63
    int r = lane & 31;
    int h = lane >> 5;

    // MFMA 32x32x16 operand layout (verified R1): A row = lane&31, k = (lane>>5)*8 + 0..7
    const float* Ap = A + (size_t)b * NN * NN + (size_t)(n0 + r) * NN + h * 8;
    const unsigned short* B0p = annT + (size_t)b * FF * NN + (size_t)r * NN + h * 8;
    const unsigned short* B1p = B0p + (size_t)32 * NN;

    f32x16 acc0 = {}, acc1 = {};

    // two named register sets, 64 k-columns (4 k16-chunks) each
    float4 aA[4][2]; uint4 bA0[4], bA1[4];
    float4 aB[4][2]; uint4 bB0[4], bB1[4];

    auto loadSet = [&](float4 (&a)[4][2], uint4 (&b0)[4], uint4 (&b1)[4], int k0) {
#pragma unroll
        for (int j = 0; j < 4; ++j) {
            int k = k0 + j * 16;
            a[j][0] = *(const float4*)(Ap + k);
            a[j][1] = *(const float4*)(Ap + k + 4);
            b0[j] = *(const uint4*)(B0p + k);
            b1[j] = *(const uint4*)(B1p + k);
        }
    };
    auto compSet = [&](float4 (&a)[4][2], uint4 (&b0)[4], uint4 (&b1)[4]) {
#pragma unroll
        for (int j = 0; j < 4; ++j) {
            uint4 ap;
            ap.x = pk2(a[j][0].x, a[j][0].y);
            ap.y = pk2(a[j][0].z, a[j][0].w);
            ap.z = pk2(a[j][1].x, a[j][1].y);
            ap.w = pk2(a[j][1].z, a[j][1].w);
            bf16x8 af = __builtin_bit_cast(bf16x8, ap);
            acc0 = __builtin_amdgcn_mfma_f32_32x32x16_bf16(
                af, __builtin_bit_cast(bf16x8, b0[j]), acc0, 0, 0, 0);
            acc1 = __builtin_amdgcn_mfma_f32_32x32x16_bf16(
                af, __builtin_bit_cast(bf16x8, b1[j]), acc1, 0, 0, 0);
        }
    };

    loadSet(aA, bA0, bA1, 0);
#pragma unroll 1
    for (int k0 = 0; k0 < NN; k0 += 128) {
        loadSet(aB, bB0, bB1, k0 + 64);
        compSet(aA, bA0, bA1);
        if (k0 + 128 < NN) loadSet(aA, bA0, bA1, k0 + 128);
        compSet(aB, bB0, bB1);
    }

    // D layout (verified R1): col = lane&31, row = (reg&3) + 8*(reg>>2) + 4*(lane>>5)
    float bv0 = bias[r], bv1 = bias[32 + r];
    float* ob = out + ((size_t)(b * NN + n0)) * FF;
#pragma unroll
    for (int t = 0; t < 16; ++t) {
        int rowl = (t & 3) + 8 * (t >> 2) + h * 4;
        ob[(size_t)rowl * FF + r] = acc0[t] + bv0;
        ob[(size_t)rowl * FF + 32 + r] = acc1[t] + bv1;
    }
}

extern "C" void kernel_launch(void* const* d_in, const int* in_sizes, int n_in,
                              void* d_out, int out_size, void* d_ws, size_t ws_size,
                              hipStream_t stream) {
    const float* adj = (const float*)d_in[0];
    const float* ann = (const float*)d_in[1];
    const float* bias = (const float*)d_in[2];
    float* out = (float*)d_out;
    unsigned short* annT = (unsigned short*)d_ws;  // 8*64*4096*2 = 4 MiB

    annT_kernel<<<dim3(8 * (NN / 64)), dim3(256), 0, stream>>>(ann, annT);
    gconv_kernel<<<dim3(8 * (NN / 32)), dim3(64), 0, stream>>>(adj, annT, bias, out);
}

// Round 3
// 707.277 us; speedup vs baseline: 1.0310x; 1.0310x over previous
//
#include <hip/hip_runtime.h>
#include <stdint.h>

typedef __bf16 bf16x8 __attribute__((ext_vector_type(8)));
typedef float f32x16 __attribute__((ext_vector_type(16)));

#define NN 4096
#define FF 64
#define BM 64
#define BK 64
#define NSTEP (NN / BK)  // 64

// round-to-nearest-even fp32 -> bf16 (for annT pre-pass)
__device__ __forceinline__ unsigned short f2bf(float x) {
    unsigned int u = __builtin_bit_cast(unsigned int, x);
    unsigned int r = u + 0x7fffu + ((u >> 16) & 1u);
    return (unsigned short)(r >> 16);
}

__device__ __forceinline__ void gload16(const void* g, void* l) {
    __builtin_amdgcn_global_load_lds((const __attribute__((address_space(1))) void*)g,
                                     (__attribute__((address_space(3))) void*)l, 16, 0, 0);
}

// Pass 1: ann[b][m][f] fp32 -> annT[b][f][m] bf16 (LDS-tiled transpose)
__global__ __launch_bounds__(256) void annT_kernel(const float* __restrict__ ann,
                                                   unsigned short* __restrict__ annT) {
    __shared__ unsigned short tile[FF * 66];
    int b = blockIdx.x >> 6;
    int m0 = (blockIdx.x & 63) << 6;
    int t = threadIdx.x;
    int f = t & 63;
    int ml = t >> 6;
    const float* src = ann + ((size_t)(b * NN + m0)) * FF;
#pragma unroll
    for (int it = 0; it < 16; ++it) {
        int m = it * 4 + ml;
        tile[f * 66 + m] = f2bf(src[(size_t)m * FF + f]);
    }
    __syncthreads();
    int m2 = (t & 31) * 2;
    int fr = t >> 5;
    unsigned short* dst = annT + (size_t)b * FF * NN + m0;
#pragma unroll
    for (int it = 0; it < 8; ++it) {
        int fo = it * 8 + fr;
        unsigned int lo = tile[fo * 66 + m2];
        unsigned int hi = tile[fo * 66 + m2 + 1];
        *(unsigned int*)(dst + (size_t)fo * NN + m2) = lo | (hi << 16);
    }
}

// Pass 2: global_load_lds staging (A fp32, B bf16), counted vmcnt(6), raw barriers.
// LDS swizzle via pre-swizzled GLOBAL source + swizzled ds_read (linear LDS dest).
__global__ __launch_bounds__(256, 2) void gconv_kernel(const float* __restrict__ A,
                                                       const unsigned short* __restrict__ annT,
                                                       const float* __restrict__ bias,
                                                       float* __restrict__ out) {
    // per buffer: A tile 64x64 fp32 = 16384 B, B tile 64x64 bf16 = 8192 B
    __shared__ alignas(16) char lds[2][24576];

    int bi = blockIdx.x;
    int b = bi & 7;              // batch == XCD -> annT[b] L2-resident per XCD
    int n0 = (bi >> 3) << 6;     // 64 row-tiles per batch
    int t = threadIdx.x, lane = t & 63, wid = t >> 6;
    int wm = wid >> 1, wf = wid & 1;
    int r = lane & 31, h = lane >> 5;

    const float* Ab = A + (size_t)b * NN * NN + (size_t)n0 * NN;
    const unsigned short* Tb = annT + (size_t)b * FF * NN;

    // --- staging source pointers (inverse-swizzled global addresses) ---
    // A: LDS slot byte s = wid*4096 + j*1024 + lane*16 holds A[row][k0 + q*4 .. +3]
    //    row = s>>8, q = ((s&255) ^ ((row&15)<<4)) >> 4
    const float* asrc[4];
#pragma unroll
    for (int j = 0; j < 4; ++j) {
        unsigned s = (unsigned)(wid * 4096 + j * 1024 + lane * 16);
        unsigned row = s >> 8;
        unsigned q = ((s & 255u) ^ ((row & 15u) << 4)) >> 4;
        asrc[j] = Ab + (size_t)row * NN + q * 4;
    }
    // B: LDS slot byte s = wid*2048 + j*1024 + lane*16 holds annT[f][k0 + q*8 .. +7]
    //    f = s>>7, q = ((s&127) ^ ((f&7)<<4)) >> 4
    const unsigned short* bsrc[2];
#pragma unroll
    for (int j = 0; j < 2; ++j) {
        unsigned s = (unsigned)(wid * 2048 + j * 1024 + lane * 16);
        unsigned f = s >> 7;
        unsigned q = ((s & 127u) ^ ((f & 7u) << 4)) >> 4;
        bsrc[j] = Tb + (size_t)f * NN + q * 8;
    }

    auto STAGE = [&](int buf, int k0) {
        char* base = lds[buf];
#pragma unroll
        for (int j = 0; j < 4; ++j)
            gload16(asrc[j] + k0, base + wid * 4096 + j * 1024);
#pragma unroll
        for (int j = 0; j < 2; ++j)
            gload16(bsrc[j] + k0, base + 16384 + wid * 2048 + j * 1024);
    };

    // --- fragment read addresses (swizzled) ---
    int arow = wm * 32 + r;
    unsigned abase = (unsigned)(arow * 256);
    unsigned aswz = (unsigned)((arow & 15) << 4);
    int frow = wf * 32 + r;
    unsigned bbase = (unsigned)(frow * 128);
    unsigned bswz = (unsigned)((frow & 7) << 4);

    f32x16 acc = {};

    STAGE(0, 0);
#pragma unroll 1
    for (int s = 0; s < NSTEP; ++s) {
        int cur = s & 1;
        if (s + 1 < NSTEP) {
            STAGE(cur ^ 1, (s + 1) * BK);
            asm volatile("s_waitcnt vmcnt(6)" ::: "memory");
        } else {
            asm volatile("s_waitcnt vmcnt(0)" ::: "memory");
        }
        __builtin_amdgcn_s_barrier();
        asm volatile("" ::: "memory");

        const char* bufA = lds[cur];
        const char* bufB = lds[cur] + 16384;
#pragma unroll
        for (int kc = 0; kc < 4; ++kc) {
            unsigned ao = abase + (unsigned)(kc * 64 + h * 32);
            float4 a0 = *(const float4*)(bufA + ((ao) ^ aswz));
            float4 a1 = *(const float4*)(bufA + ((ao + 16) ^ aswz));
            bf16x8 af = {(__bf16)a0.x, (__bf16)a0.y, (__bf16)a0.z, (__bf16)a0.w,
                         (__bf16)a1.x, (__bf16)a1.y, (__bf16)a1.z, (__bf16)a1.w};
            unsigned bo = (bbase + (unsigned)(kc * 32 + h * 16)) ^ bswz;
            bf16x8 bf = *(const bf16x8*)(bufB + bo);
            acc = __builtin_amdgcn_mfma_f32_32x32x16_bf16(af, bf, acc, 0, 0, 0);
        }
        asm volatile("" ::: "memory");
        __builtin_amdgcn_s_barrier();
        asm volatile("" ::: "memory");
    }

    // epilogue: D col = lane&31, row = (reg&3) + 8*(reg>>2) + 4*(lane>>5)  (verified R1/R2)
    float bv = bias[wf * 32 + r];
    float* ob = out + ((size_t)(b * NN + n0 + wm * 32)) * FF + wf * 32 + r;
#pragma unroll
    for (int e = 0; e < 16; ++e) {
        int rowl = (e & 3) + 8 * (e >> 2) + h * 4;
        ob[(size_t)rowl * FF] = acc[e] + bv;
    }
}

extern "C" void kernel_launch(void* const* d_in, const int* in_sizes, int n_in,
                              void* d_out, int out_size, void* d_ws, size_t ws_size,
                              hipStream_t stream) {
    const float* adj = (const float*)d_in[0];
    const float* ann = (const float*)d_in[1];
    const float* bias = (const float*)d_in[2];
    float* out = (float*)d_out;
    unsigned short* annT = (unsigned short*)d_ws;  // 8*64*4096*2 = 4 MiB

    annT_kernel<<<dim3(8 * (NN / 64)), dim3(256), 0, stream>>>(ann, annT);
    gconv_kernel<<<dim3(8 * (NN / BM)), dim3(256), 0, stream>>>(adj, annT, bias, out);
}